// Round 1
// baseline (8758.796 us; speedup 1.0000x reference)
//
#include <hip/hip_runtime.h>
#include <hip/hip_bf16.h>

#define NN 50000
#define NE 1600000
#define FIN 128
#define HH 256
#define GG 64
#define AA 16

// ---------------- degree histograms ----------------
__global__ void k_deg(const int* __restrict__ dst, float* __restrict__ cnt) {
    int e = blockIdx.x * 256 + threadIdx.x;
    if (e < NE) atomicAdd(&cnt[dst[e]], 1.0f);
}

__global__ void k_gdeg(const int* __restrict__ batch, float* __restrict__ gcnt) {
    __shared__ float h[GG];
    int t = threadIdx.x;
    if (t < GG) h[t] = 0.0f;
    __syncthreads();
    int i = blockIdx.x * 256 + t;
    if (i < NN) atomicAdd(&h[batch[i]], 1.0f);
    __syncthreads();
    if (t < GG && h[t] != 0.0f) atomicAdd(&gcnt[t], h[t]);
}

// ---------------- edge scatter (mean-agg numerator) ----------------
// C threads per edge, each thread handles 4 consecutive floats (float4 read).
template<int C>
__global__ void k_scatter(const int* __restrict__ src, const int* __restrict__ dst,
                          const float* __restrict__ feat, float* __restrict__ agg) {
    long long tid = (long long)blockIdx.x * 256 + threadIdx.x;
    if (tid >= (long long)NE * C) return;
    int e = (int)(tid / C);
    int c = (int)(tid % C);
    int s = src[e], d = dst[e];
    float4 v = reinterpret_cast<const float4*>(feat)[s * C + c];
    float* a = agg + (d * C + c) * 4;
    atomicAdd(a + 0, v.x);
    atomicAdd(a + 1, v.y);
    atomicAdd(a + 2, v.z);
    atomicAdd(a + 3, v.w);
}

// ---------------- SAGE layer: out = relu( (agg/cnt)@Wl + bl + xin@Wr ) ----------------
// K = 2*KH total contraction (KH mean dims + KH self dims). NPB nodes per block.
// Thread j owns output column j; u staged in LDS, broadcast-read; weight reads
// coalesced across j and L2-resident.
template<int K, int NPB>
__global__ void __launch_bounds__(256) k_sage(
        const float* __restrict__ agg, const float* __restrict__ xin,
        const float* __restrict__ cnt,
        const float* __restrict__ Wl, const float* __restrict__ bl,
        const float* __restrict__ Wr, float* __restrict__ out) {
    constexpr int KH = K / 2;
    __shared__ float u[NPB][K];
    const int j = threadIdx.x;
    const int base = blockIdx.x * NPB;

    for (int idx = j; idx < NPB * K; idx += 256) {
        int m = idx / K, k = idx % K;
        int node = base + m;
        float v = 0.0f;
        if (node < NN) {
            if (k < KH) {
                float c = cnt[node];
                c = c > 1.0f ? c : 1.0f;
                v = agg[node * KH + k] * __builtin_amdgcn_rcpf(c);
            } else {
                v = xin[node * KH + (k - KH)];
            }
        }
        u[m][k] = v;
    }
    __syncthreads();

    float acc[NPB];
#pragma unroll
    for (int m = 0; m < NPB; m++) acc[m] = 0.0f;

#pragma unroll 2
    for (int k = 0; k < KH; k += 4) {
        const float* W = Wl + k * HH + j;
        float w0 = W[0], w1 = W[HH], w2 = W[2 * HH], w3 = W[3 * HH];
#pragma unroll
        for (int m = 0; m < NPB; m++) {
            float4 uv = *reinterpret_cast<const float4*>(&u[m][k]);
            acc[m] += uv.x * w0 + uv.y * w1 + uv.z * w2 + uv.w * w3;
        }
    }
#pragma unroll 2
    for (int k = 0; k < KH; k += 4) {
        const float* W = Wr + k * HH + j;
        float w0 = W[0], w1 = W[HH], w2 = W[2 * HH], w3 = W[3 * HH];
#pragma unroll
        for (int m = 0; m < NPB; m++) {
            float4 uv = *reinterpret_cast<const float4*>(&u[m][KH + k]);
            acc[m] += uv.x * w0 + uv.y * w1 + uv.z * w2 + uv.w * w3;
        }
    }

    float b = bl[j];
#pragma unroll
    for (int m = 0; m < NPB; m++) {
        int node = base + m;
        if (node < NN) {
            float r = acc[m] + b;
            out[node * HH + j] = r > 0.0f ? r : 0.0f;
        }
    }
}

// ---------------- global mean pool (batch is SORTED) ----------------
// Block handles 256 consecutive nodes; thread j owns feature j; running sum
// flushed via atomicAdd only on graph-id change (~1-2 atomics/thread).
__global__ void k_pool(const float* __restrict__ h, const int* __restrict__ batch,
                       float* __restrict__ gpool) {
    __shared__ int sb[256];
    int j = threadIdx.x;
    int base = blockIdx.x * 256;
    int n = NN - base; if (n > 256) n = 256;
    if (j < n) sb[j] = batch[base + j];
    __syncthreads();
    float acc = 0.0f;
    int cur = sb[0];
    for (int t = 0; t < n; t++) {
        int g = sb[t];
        if (g != cur) {
            atomicAdd(&gpool[cur * HH + j], acc);
            acc = 0.0f;
            cur = g;
        }
        acc += h[(base + t) * HH + j];
    }
    atomicAdd(&gpool[cur * HH + j], acc);
}

// ---------------- heads: one block per graph ----------------
__global__ void k_head(const float* __restrict__ gpool, const float* __restrict__ gcnt,
                       const float* __restrict__ Wa1, const float* __restrict__ ba1,
                       const float* __restrict__ Wa2, const float* __restrict__ ba2,
                       const float* __restrict__ Wc1, const float* __restrict__ bc1,
                       const float* __restrict__ Wc2, const float* __restrict__ bc2,
                       float* __restrict__ outp) {
    __shared__ float gv[HH], ha[HH], hc[HH];
    int g = blockIdx.x, j = threadIdx.x;
    float c = gcnt[g];
    c = c > 1.0f ? c : 1.0f;
    gv[j] = gpool[g * HH + j] * __builtin_amdgcn_rcpf(c);
    __syncthreads();
    float a_acc = ba1[j], c_acc = bc1[j];
#pragma unroll 2
    for (int k = 0; k < HH; k += 4) {
        float4 g4 = *reinterpret_cast<const float4*>(&gv[k]);
        const float* WA = Wa1 + k * HH + j;
        const float* WC = Wc1 + k * HH + j;
        a_acc += g4.x * WA[0] + g4.y * WA[HH] + g4.z * WA[2 * HH] + g4.w * WA[3 * HH];
        c_acc += g4.x * WC[0] + g4.y * WC[HH] + g4.z * WC[2 * HH] + g4.w * WC[3 * HH];
    }
    ha[j] = a_acc > 0.0f ? a_acc : 0.0f;
    hc[j] = c_acc > 0.0f ? c_acc : 0.0f;
    __syncthreads();
    if (j < AA) {
        float m = ba2[j];
        for (int k = 0; k < HH; k++) m += ha[k] * Wa2[k * AA + j];
        outp[g * AA + j] = m;
    } else if (j == AA) {
        float v = bc2[0];
        for (int k = 0; k < HH; k++) v += hc[k] * Wc2[k];
        outp[GG * AA + g] = v;
    }
}

extern "C" void kernel_launch(void* const* d_in, const int* in_sizes, int n_in,
                              void* d_out, int out_size, void* d_ws, size_t ws_size,
                              hipStream_t stream) {
    const float* x     = (const float*)d_in[0];
    const int*   ei    = (const int*)d_in[1];
    const int*   batch = (const int*)d_in[2];
    const float* Wl1 = (const float*)d_in[3];
    const float* bl1 = (const float*)d_in[4];
    const float* Wr1 = (const float*)d_in[5];
    const float* Wl2 = (const float*)d_in[6];
    const float* bl2 = (const float*)d_in[7];
    const float* Wr2 = (const float*)d_in[8];
    const float* Wa1 = (const float*)d_in[9];
    const float* ba1 = (const float*)d_in[10];
    const float* Wa2 = (const float*)d_in[11];
    const float* ba2 = (const float*)d_in[12];
    const float* Wc1 = (const float*)d_in[13];
    const float* bc1 = (const float*)d_in[14];
    const float* Wc2 = (const float*)d_in[15];
    const float* bc2 = (const float*)d_in[16];
    float* out = (float*)d_out;

    const int* srcv = ei;       // edge_index[0]
    const int* dstv = ei + NE;  // edge_index[1]

    // workspace layout (bytes, 256-aligned)
    char* ws = (char*)d_ws;
    float* cnt   = (float*)(ws + 0);        // N floats        (200000 B)
    float* gcnt  = (float*)(ws + 200192);   // G floats
    float* gpool = (float*)(ws + 200448);   // G*H floats      (65536 B)
    float* P     = (float*)(ws + 266240);   // N*H floats: agg1(128-wide)/agg2/h2
    float* Q     = (float*)(ws + 51466240); // N*H floats: h1
    // total ~102.7 MB

    hipMemsetAsync(ws, 0, 265984, stream);                       // cnt, gcnt, gpool
    hipMemsetAsync(P, 0, (size_t)NN * FIN * 4, stream);          // agg1

    k_deg <<<(NE + 255) / 256, 256, 0, stream>>>(dstv, cnt);
    k_gdeg<<<(NN + 255) / 256, 256, 0, stream>>>(batch, gcnt);

    // layer 1
    k_scatter<32><<<(int)(((long long)NE * 32) / 256), 256, 0, stream>>>(srcv, dstv, x, P);
    k_sage<256, 16><<<(NN + 15) / 16, 256, 0, stream>>>(P, x, cnt, Wl1, bl1, Wr1, Q);

    // layer 2
    hipMemsetAsync(P, 0, (size_t)NN * HH * 4, stream);           // agg2
    k_scatter<64><<<(int)(((long long)NE * 64) / 256), 256, 0, stream>>>(srcv, dstv, Q, P);
    k_sage<512, 16><<<(NN + 15) / 16, 256, 0, stream>>>(P, Q, cnt, Wl2, bl2, Wr2, P); // h2 in-place

    // pool + heads
    k_pool<<<(NN + 255) / 256, 256, 0, stream>>>(P, batch, gpool);
    k_head<<<GG, 256, 0, stream>>>(gpool, gcnt, Wa1, ba1, Wa2, ba2, Wc1, bc1, Wc2, bc2, out);
}

// Round 2
// 1123.811 us; speedup vs baseline: 7.7938x; 7.7938x over previous
//
#include <hip/hip_runtime.h>
#include <hip/hip_bf16.h>

#define NN 50000
#define NE 1600000
#define FIN 128
#define HH 256
#define GG 64
#define AA 16
#define NB ((NN + 255) / 256)   // 196 scan blocks

// ---------------- degree histograms ----------------
__global__ void k_degi(const int* __restrict__ dst, int* __restrict__ degi) {
    int e = blockIdx.x * 256 + threadIdx.x;
    if (e < NE) atomicAdd(&degi[dst[e]], 1);
}

__global__ void k_gdeg(const int* __restrict__ batch, float* __restrict__ gcnt) {
    __shared__ float h[GG];
    int t = threadIdx.x;
    if (t < GG) h[t] = 0.0f;
    __syncthreads();
    int i = blockIdx.x * 256 + t;
    if (i < NN) atomicAdd(&h[batch[i]], 1.0f);
    __syncthreads();
    if (t < GG && h[t] != 0.0f) atomicAdd(&gcnt[t], h[t]);
}

// ---------------- prefix sum over degrees (3 tiny kernels) ----------------
__global__ void k_scan1(const int* __restrict__ degi, int* __restrict__ blocksum) {
    __shared__ int s[256];
    int t = threadIdx.x, i = blockIdx.x * 256 + t;
    s[t] = i < NN ? degi[i] : 0;
    __syncthreads();
    for (int d = 128; d > 0; d >>= 1) { if (t < d) s[t] += s[t + d]; __syncthreads(); }
    if (t == 0) blocksum[blockIdx.x] = s[0];
}

__global__ void k_scan2(const int* __restrict__ blocksum, int* __restrict__ blockoff) {
    __shared__ int s[256];
    int t = threadIdx.x;
    int v = t < NB ? blocksum[t] : 0;
    s[t] = v; __syncthreads();
    for (int d = 1; d < 256; d <<= 1) {
        int x = t >= d ? s[t - d] : 0; __syncthreads();
        s[t] += x; __syncthreads();
    }
    if (t < NB) blockoff[t] = s[t] - v;   // exclusive
}

__global__ void k_scan3(const int* __restrict__ degi, const int* __restrict__ blockoff,
                        int* __restrict__ offsets, int* __restrict__ cursor) {
    __shared__ int s[256];
    int t = threadIdx.x, i = blockIdx.x * 256 + t;
    int v = i < NN ? degi[i] : 0;
    s[t] = v; __syncthreads();
    for (int d = 1; d < 256; d <<= 1) {
        int x = t >= d ? s[t - d] : 0; __syncthreads();
        s[t] += x; __syncthreads();
    }
    if (i < NN) {
        int off = blockoff[blockIdx.x] + s[t] - v;   // exclusive global
        offsets[i] = off;
        cursor[i]  = off;
    }
    if (i == 0) offsets[NN] = NE;
}

// ---------------- CSR fill ----------------
__global__ void k_fill(const int* __restrict__ src, const int* __restrict__ dst,
                       int* __restrict__ cursor, int* __restrict__ csr_src) {
    int e = blockIdx.x * 256 + threadIdx.x;
    if (e < NE) {
        int slot = atomicAdd(&cursor[dst[e]], 1);
        csr_src[slot] = src[e];
    }
}

// ---------------- gather mean-aggregation: one wave per node ----------------
// Writes MEAN directly (normalized by max(deg,1)).
template<int C>
__global__ void __launch_bounds__(256) k_gather(
        const int* __restrict__ offsets, const int* __restrict__ csr_src,
        const float* __restrict__ feat, float* __restrict__ agg) {
    constexpr int V = C / 64;                  // floats per lane: 2 (C=128) or 4 (C=256)
    int wid = threadIdx.x >> 6, lane = threadIdx.x & 63;
    int node = blockIdx.x * 4 + wid;
    if (node >= NN) return;
    int o0 = offsets[node], o1 = offsets[node + 1];
    float acc[V];
#pragma unroll
    for (int i = 0; i < V; i++) acc[i] = 0.0f;

    int t = o0;
    for (; t + 1 < o1; t += 2) {               // 2-way MLP unroll
        int s0 = csr_src[t], s1 = csr_src[t + 1];
        const float* f0 = feat + (size_t)s0 * C + lane * V;
        const float* f1 = feat + (size_t)s1 * C + lane * V;
        if (V == 2) {
            float2 a = *(const float2*)f0, b = *(const float2*)f1;
            acc[0] += a.x + b.x; acc[1] += a.y + b.y;
        } else {
            float4 a = *(const float4*)f0, b = *(const float4*)f1;
            acc[0] += a.x + b.x; acc[1] += a.y + b.y;
            acc[2] += a.z + b.z; acc[3] += a.w + b.w;
        }
    }
    if (t < o1) {
        int s0 = csr_src[t];
        const float* f0 = feat + (size_t)s0 * C + lane * V;
        if (V == 2) {
            float2 a = *(const float2*)f0;
            acc[0] += a.x; acc[1] += a.y;
        } else {
            float4 a = *(const float4*)f0;
            acc[0] += a.x; acc[1] += a.y; acc[2] += a.z; acc[3] += a.w;
        }
    }

    int deg = o1 - o0;
    float r = __builtin_amdgcn_rcpf(deg > 1 ? (float)deg : 1.0f);
    float* o = agg + (size_t)node * C + lane * V;
#pragma unroll
    for (int i = 0; i < V; i++) o[i] = acc[i] * r;
}

// ---------------- SAGE layer: out = relu( agg@Wl + bl + xin@Wr ) ----------------
// agg already holds the mean. Thread j owns output column j.
template<int K, int NPB>
__global__ void __launch_bounds__(256) k_sage(
        const float* __restrict__ agg, const float* __restrict__ xin,
        const float* __restrict__ Wl, const float* __restrict__ bl,
        const float* __restrict__ Wr, float* __restrict__ out) {
    constexpr int KH = K / 2;
    __shared__ float u[NPB][K];
    const int j = threadIdx.x;
    const int base = blockIdx.x * NPB;

    for (int idx = j; idx < NPB * K; idx += 256) {
        int m = idx / K, k = idx % K;
        int node = base + m;
        float v = 0.0f;
        if (node < NN)
            v = (k < KH) ? agg[(size_t)node * KH + k] : xin[(size_t)node * KH + (k - KH)];
        u[m][k] = v;
    }
    __syncthreads();

    float acc[NPB];
#pragma unroll
    for (int m = 0; m < NPB; m++) acc[m] = 0.0f;

#pragma unroll 2
    for (int k = 0; k < KH; k += 4) {
        const float* W = Wl + k * HH + j;
        float w0 = W[0], w1 = W[HH], w2 = W[2 * HH], w3 = W[3 * HH];
#pragma unroll
        for (int m = 0; m < NPB; m++) {
            float4 uv = *reinterpret_cast<const float4*>(&u[m][k]);
            acc[m] += uv.x * w0 + uv.y * w1 + uv.z * w2 + uv.w * w3;
        }
    }
#pragma unroll 2
    for (int k = 0; k < KH; k += 4) {
        const float* W = Wr + k * HH + j;
        float w0 = W[0], w1 = W[HH], w2 = W[2 * HH], w3 = W[3 * HH];
#pragma unroll
        for (int m = 0; m < NPB; m++) {
            float4 uv = *reinterpret_cast<const float4*>(&u[m][KH + k]);
            acc[m] += uv.x * w0 + uv.y * w1 + uv.z * w2 + uv.w * w3;
        }
    }

    float b = bl[j];
#pragma unroll
    for (int m = 0; m < NPB; m++) {
        int node = base + m;
        if (node < NN) {
            float r = acc[m] + b;
            out[(size_t)node * HH + j] = r > 0.0f ? r : 0.0f;
        }
    }
}

// ---------------- global mean pool (batch is SORTED) ----------------
__global__ void k_pool(const float* __restrict__ h, const int* __restrict__ batch,
                       float* __restrict__ gpool) {
    __shared__ int sb[256];
    int j = threadIdx.x;
    int base = blockIdx.x * 256;
    int n = NN - base; if (n > 256) n = 256;
    if (j < n) sb[j] = batch[base + j];
    __syncthreads();
    float acc = 0.0f;
    int cur = sb[0];
    for (int t = 0; t < n; t++) {
        int g = sb[t];
        if (g != cur) {
            atomicAdd(&gpool[cur * HH + j], acc);
            acc = 0.0f;
            cur = g;
        }
        acc += h[(size_t)(base + t) * HH + j];
    }
    atomicAdd(&gpool[cur * HH + j], acc);
}

// ---------------- heads: one block per graph ----------------
__global__ void k_head(const float* __restrict__ gpool, const float* __restrict__ gcnt,
                       const float* __restrict__ Wa1, const float* __restrict__ ba1,
                       const float* __restrict__ Wa2, const float* __restrict__ ba2,
                       const float* __restrict__ Wc1, const float* __restrict__ bc1,
                       const float* __restrict__ Wc2, const float* __restrict__ bc2,
                       float* __restrict__ outp) {
    __shared__ float gv[HH], ha[HH], hc[HH];
    int g = blockIdx.x, j = threadIdx.x;
    float c = gcnt[g];
    c = c > 1.0f ? c : 1.0f;
    gv[j] = gpool[g * HH + j] * __builtin_amdgcn_rcpf(c);
    __syncthreads();
    float a_acc = ba1[j], c_acc = bc1[j];
#pragma unroll 2
    for (int k = 0; k < HH; k += 4) {
        float4 g4 = *reinterpret_cast<const float4*>(&gv[k]);
        const float* WA = Wa1 + k * HH + j;
        const float* WC = Wc1 + k * HH + j;
        a_acc += g4.x * WA[0] + g4.y * WA[HH] + g4.z * WA[2 * HH] + g4.w * WA[3 * HH];
        c_acc += g4.x * WC[0] + g4.y * WC[HH] + g4.z * WC[2 * HH] + g4.w * WC[3 * HH];
    }
    ha[j] = a_acc > 0.0f ? a_acc : 0.0f;
    hc[j] = c_acc > 0.0f ? c_acc : 0.0f;
    __syncthreads();
    if (j < AA) {
        float m = ba2[j];
        for (int k = 0; k < HH; k++) m += ha[k] * Wa2[k * AA + j];
        outp[g * AA + j] = m;
    } else if (j == AA) {
        float v = bc2[0];
        for (int k = 0; k < HH; k++) v += hc[k] * Wc2[k];
        outp[GG * AA + g] = v;
    }
}

extern "C" void kernel_launch(void* const* d_in, const int* in_sizes, int n_in,
                              void* d_out, int out_size, void* d_ws, size_t ws_size,
                              hipStream_t stream) {
    const float* x     = (const float*)d_in[0];
    const int*   ei    = (const int*)d_in[1];
    const int*   batch = (const int*)d_in[2];
    const float* Wl1 = (const float*)d_in[3];
    const float* bl1 = (const float*)d_in[4];
    const float* Wr1 = (const float*)d_in[5];
    const float* Wl2 = (const float*)d_in[6];
    const float* bl2 = (const float*)d_in[7];
    const float* Wr2 = (const float*)d_in[8];
    const float* Wa1 = (const float*)d_in[9];
    const float* ba1 = (const float*)d_in[10];
    const float* Wa2 = (const float*)d_in[11];
    const float* ba2 = (const float*)d_in[12];
    const float* Wc1 = (const float*)d_in[13];
    const float* bc1 = (const float*)d_in[14];
    const float* Wc2 = (const float*)d_in[15];
    const float* bc2 = (const float*)d_in[16];
    float* out = (float*)d_out;

    const int* srcv = ei;       // edge_index[0]
    const int* dstv = ei + NE;  // edge_index[1]

    // workspace layout (bytes, 256-aligned)
    char* ws = (char*)d_ws;
    int*   degi     = (int*)(ws + 0);         // N ints       (200000 B)
    int*   offsets  = (int*)(ws + 200192);    // N+1 ints
    int*   cursor   = (int*)(ws + 400640);    // N ints
    int*   blocksum = (int*)(ws + 600832);    // NB ints
    int*   blockoff = (int*)(ws + 601856);    // NB ints
    float* gcnt     = (float*)(ws + 602880);  // G floats
    float* gpool    = (float*)(ws + 603136);  // G*H floats   (65536 B)
    int*   csr_src  = (int*)(ws + 668672);    // E ints       (6400000 B)
    float* P        = (float*)(ws + 7068672); // N*H floats: agg1/agg2/h2
    float* Q        = (float*)(ws + 58268672);// N*H floats: h1
    // total ~109.5 MB

    hipMemsetAsync(ws, 0, 200192, stream);            // degi
    hipMemsetAsync(ws + 602880, 0, 65792, stream);    // gcnt + gpool

    k_degi<<<(NE + 255) / 256, 256, 0, stream>>>(dstv, degi);
    k_gdeg<<<(NN + 255) / 256, 256, 0, stream>>>(batch, gcnt);
    k_scan1<<<NB, 256, 0, stream>>>(degi, blocksum);
    k_scan2<<<1, 256, 0, stream>>>(blocksum, blockoff);
    k_scan3<<<NB, 256, 0, stream>>>(degi, blockoff, offsets, cursor);
    k_fill<<<(NE + 255) / 256, 256, 0, stream>>>(srcv, dstv, cursor, csr_src);

    // layer 1: gather mean of x, then GEMM
    k_gather<FIN><<<(NN + 3) / 4, 256, 0, stream>>>(offsets, csr_src, x, P);
    k_sage<2 * FIN, 16><<<(NN + 15) / 16, 256, 0, stream>>>(P, x, Wl1, bl1, Wr1, Q);

    // layer 2: gather mean of h1, then GEMM (h2 in-place over P)
    k_gather<HH><<<(NN + 3) / 4, 256, 0, stream>>>(offsets, csr_src, Q, P);
    k_sage<2 * HH, 16><<<(NN + 15) / 16, 256, 0, stream>>>(P, Q, Wl2, bl2, Wr2, P);

    // pool + heads
    k_pool<<<(NN + 255) / 256, 256, 0, stream>>>(P, batch, gpool);
    k_head<<<GG, 256, 0, stream>>>(gpool, gcnt, Wa1, ba1, Wa2, ba2, Wc1, bc1, Wc2, bc2, out);
}

// Round 3
// 596.178 us; speedup vs baseline: 14.6916x; 1.8850x over previous
//
#include <hip/hip_runtime.h>
#include <hip/hip_bf16.h>

#define NN 50000
#define NE 1600000
#define FIN 128
#define HH 256
#define GG 64
#define AA 16
#define NB ((NN + 255) / 256)   // 196 scan blocks

typedef __attribute__((ext_vector_type(8))) short short8;
typedef __attribute__((ext_vector_type(4))) float f32x4;

static __device__ __forceinline__ ushort f2b(float f) {
    union { __hip_bfloat16 h; ushort u; } v; v.h = __float2bfloat16(f); return v.u;
}
static __device__ __forceinline__ float b2f_lo(uint a) {   // low ushort
    union { float f; uint u; } v; v.u = a << 16; return v.f;
}
static __device__ __forceinline__ float b2f_hi(uint a) {   // high ushort
    union { float f; uint u; } v; v.u = a & 0xFFFF0000u; return v.f;
}

// ---------------- casts ----------------
__global__ void k_castx(const float* __restrict__ x, ushort* __restrict__ xb) {
    int i = blockIdx.x * 256 + threadIdx.x;            // one float4 per thread
    if (i >= NN * FIN / 4) return;
    float4 v = reinterpret_cast<const float4*>(x)[i];
    ushort4 o; o.x = f2b(v.x); o.y = f2b(v.y); o.z = f2b(v.z); o.w = f2b(v.w);
    reinterpret_cast<ushort4*>(xb)[i] = o;
}

// Wt[n][k] = (k<KH ? Wl[k][n] : Wr[k-KH][n]), bf16, row stride K
template<int K>
__global__ void k_castw(const float* __restrict__ Wl, const float* __restrict__ Wr,
                        ushort* __restrict__ Wt) {
    constexpr int KH = K / 2;
    int t = blockIdx.x * 256 + threadIdx.x;
    if (t >= HH * K) return;
    int n = t / K, k = t % K;
    float v = (k < KH) ? Wl[k * HH + n] : Wr[(k - KH) * HH + n];
    Wt[t] = f2b(v);
}

// ---------------- degree histograms ----------------
__global__ void k_degi(const int* __restrict__ dst, int* __restrict__ degi) {
    int e = blockIdx.x * 256 + threadIdx.x;
    if (e < NE) atomicAdd(&degi[dst[e]], 1);
}

__global__ void k_gdeg(const int* __restrict__ batch, float* __restrict__ gcnt) {
    __shared__ float h[GG];
    int t = threadIdx.x;
    if (t < GG) h[t] = 0.0f;
    __syncthreads();
    int i = blockIdx.x * 256 + t;
    if (i < NN) atomicAdd(&h[batch[i]], 1.0f);
    __syncthreads();
    if (t < GG && h[t] != 0.0f) atomicAdd(&gcnt[t], h[t]);
}

// ---------------- prefix sum over degrees ----------------
__global__ void k_scan1(const int* __restrict__ degi, int* __restrict__ blocksum) {
    __shared__ int s[256];
    int t = threadIdx.x, i = blockIdx.x * 256 + t;
    s[t] = i < NN ? degi[i] : 0;
    __syncthreads();
    for (int d = 128; d > 0; d >>= 1) { if (t < d) s[t] += s[t + d]; __syncthreads(); }
    if (t == 0) blocksum[blockIdx.x] = s[0];
}

__global__ void k_scan2(const int* __restrict__ blocksum, int* __restrict__ blockoff) {
    __shared__ int s[256];
    int t = threadIdx.x;
    int v = t < NB ? blocksum[t] : 0;
    s[t] = v; __syncthreads();
    for (int d = 1; d < 256; d <<= 1) {
        int x = t >= d ? s[t - d] : 0; __syncthreads();
        s[t] += x; __syncthreads();
    }
    if (t < NB) blockoff[t] = s[t] - v;
}

__global__ void k_scan3(const int* __restrict__ degi, const int* __restrict__ blockoff,
                        int* __restrict__ offsets, int* __restrict__ cursor) {
    __shared__ int s[256];
    int t = threadIdx.x, i = blockIdx.x * 256 + t;
    int v = i < NN ? degi[i] : 0;
    s[t] = v; __syncthreads();
    for (int d = 1; d < 256; d <<= 1) {
        int x = t >= d ? s[t - d] : 0; __syncthreads();
        s[t] += x; __syncthreads();
    }
    if (i < NN) {
        int off = blockoff[blockIdx.x] + s[t] - v;
        offsets[i] = off;
        cursor[i]  = off;
    }
    if (i == 0) offsets[NN] = NE;
}

__global__ void k_fill(const int* __restrict__ src, const int* __restrict__ dst,
                       int* __restrict__ cursor, int* __restrict__ csr_src) {
    int e = blockIdx.x * 256 + threadIdx.x;
    if (e < NE) {
        int slot = atomicAdd(&cursor[dst[e]], 1);
        csr_src[slot] = src[e];
    }
}

// ---------------- gather mean-aggregation (bf16 in / bf16 out) ----------------
template<int C>
__global__ void __launch_bounds__(256) k_gatherb(
        const int* __restrict__ offsets, const int* __restrict__ csr_src,
        const ushort* __restrict__ feat, ushort* __restrict__ agg) {
    constexpr int V = C / 64;                  // bf16 per lane: 2 or 4
    int wid = threadIdx.x >> 6, lane = threadIdx.x & 63;
    int node = blockIdx.x * 4 + wid;
    if (node >= NN) return;
    int o0 = offsets[node], o1 = offsets[node + 1];
    float acc[V];
#pragma unroll
    for (int i = 0; i < V; i++) acc[i] = 0.0f;

    int t = o0;
    for (; t + 1 < o1; t += 2) {
        int s0 = csr_src[t], s1 = csr_src[t + 1];
        if (V == 2) {
            uint a = *(const uint*)(feat + (size_t)s0 * C + lane * 2);
            uint b = *(const uint*)(feat + (size_t)s1 * C + lane * 2);
            acc[0] += b2f_lo(a) + b2f_lo(b);
            acc[1] += b2f_hi(a) + b2f_hi(b);
        } else {
            uint2 a = *(const uint2*)(feat + (size_t)s0 * C + lane * 4);
            uint2 b = *(const uint2*)(feat + (size_t)s1 * C + lane * 4);
            acc[0] += b2f_lo(a.x) + b2f_lo(b.x);
            acc[1] += b2f_hi(a.x) + b2f_hi(b.x);
            acc[2] += b2f_lo(a.y) + b2f_lo(b.y);
            acc[3] += b2f_hi(a.y) + b2f_hi(b.y);
        }
    }
    if (t < o1) {
        int s0 = csr_src[t];
        if (V == 2) {
            uint a = *(const uint*)(feat + (size_t)s0 * C + lane * 2);
            acc[0] += b2f_lo(a); acc[1] += b2f_hi(a);
        } else {
            uint2 a = *(const uint2*)(feat + (size_t)s0 * C + lane * 4);
            acc[0] += b2f_lo(a.x); acc[1] += b2f_hi(a.x);
            acc[2] += b2f_lo(a.y); acc[3] += b2f_hi(a.y);
        }
    }

    int deg = o1 - o0;
    float r = __builtin_amdgcn_rcpf(deg > 1 ? (float)deg : 1.0f);
    if (V == 2) {
        uint o = (uint)f2b(acc[0] * r) | ((uint)f2b(acc[1] * r) << 16);
        *(uint*)(agg + (size_t)node * C + lane * 2) = o;
    } else {
        uint2 o;
        o.x = (uint)f2b(acc[0] * r) | ((uint)f2b(acc[1] * r) << 16);
        o.y = (uint)f2b(acc[2] * r) | ((uint)f2b(acc[3] * r) << 16);
        *(uint2*)(agg + (size_t)node * C + lane * 4) = o;
    }
}

// ---------------- SAGE layer via MFMA ----------------
// out[64 nodes x 256 cols] per block; A = [agg | xin] (row stride KH each, bf16),
// B = Wt (256 rows x K, transposed stacked weights, bf16). 4 waves: wave w owns
// cols [w*64, w*64+64). out may alias agg (in-place, see barrier discipline).
template<int K>
__global__ void __launch_bounds__(256) k_sage_mfma(
        const ushort* __restrict__ agg, const ushort* __restrict__ xin,
        const ushort* __restrict__ Wt, const float* __restrict__ bias,
        ushort* __restrict__ outb) {
    constexpr int KH = K / 2;
    constexpr int LDP = 40;                    // padded row stride (shorts): 80B, 16B-aligned
    __shared__ ushort As[64 * LDP];            // 64 nodes x 32 k
    __shared__ ushort Bs[256 * LDP];           // 256 cols x 32 k

    const int tid  = threadIdx.x;
    const int lane = tid & 63;
    const int w    = tid >> 6;
    const int base = blockIdx.x * 64;
    const int r    = lane & 15;
    const int kh   = lane >> 4;                // 0..3
    const int wcol = w * 64;

    f32x4 acc[4][4];
#pragma unroll
    for (int m = 0; m < 4; m++)
#pragma unroll
        for (int n = 0; n < 4; n++) acc[m][n] = (f32x4){0.f, 0.f, 0.f, 0.f};

    const int frow = tid >> 2;                 // fill row 0..63
    const int fq   = tid & 3;                  // fill 8-short quarter
    int fnode = base + frow; if (fnode >= NN) fnode = 0;

    for (int k0 = 0; k0 < K; k0 += 32) {
        __syncthreads();                       // prev step's LDS reads done
        // stage A tile: 64 rows x 32 k
        {
            const ushort* srcp = (k0 < KH)
                ? agg + (size_t)fnode * KH + k0 + fq * 8
                : xin + (size_t)fnode * KH + (k0 - KH) + fq * 8;
            *(uint4*)(&As[frow * LDP + fq * 8]) = *(const uint4*)srcp;
        }
        // stage B tile: 256 rows x 32 k (4 sweeps of 64 rows)
#pragma unroll
        for (int s = 0; s < 4; s++) {
            int c = frow + s * 64;
            *(uint4*)(&Bs[c * LDP + fq * 8]) =
                *(const uint4*)(Wt + (size_t)c * K + k0 + fq * 8);
        }
        __syncthreads();

        short8 av[4], bv[4];
#pragma unroll
        for (int m = 0; m < 4; m++)
            av[m] = *(const short8*)(&As[(m * 16 + r) * LDP + kh * 8]);
#pragma unroll
        for (int n = 0; n < 4; n++)
            bv[n] = *(const short8*)(&Bs[(wcol + n * 16 + r) * LDP + kh * 8]);
#pragma unroll
        for (int m = 0; m < 4; m++)
#pragma unroll
            for (int n = 0; n < 4; n++)
                acc[m][n] = __builtin_amdgcn_mfma_f32_16x16x32_bf16(
                    av[m], bv[n], acc[m][n], 0, 0, 0);
    }

    // epilogue: bias + relu + bf16 store. C layout: col=lane&15, row=(lane>>4)*4+reg.
    float bj[4];
#pragma unroll
    for (int n = 0; n < 4; n++) bj[n] = bias[wcol + n * 16 + r];

#pragma unroll
    for (int m = 0; m < 4; m++) {
        int rowbase = base + m * 16 + (lane >> 4) * 4;
#pragma unroll
        for (int reg = 0; reg < 4; reg++) {
            int nd = rowbase + reg;
            if (nd < NN) {
#pragma unroll
                for (int n = 0; n < 4; n++) {
                    float v = acc[m][n][reg] + bj[n];
                    v = v > 0.0f ? v : 0.0f;
                    outb[(size_t)nd * HH + wcol + n * 16 + r] = f2b(v);
                }
            }
        }
    }
}

// ---------------- global mean pool (bf16 input, batch SORTED) ----------------
__global__ void k_pool(const ushort* __restrict__ h, const int* __restrict__ batch,
                       float* __restrict__ gpool) {
    __shared__ int sb[256];
    int j = threadIdx.x;
    int base = blockIdx.x * 256;
    int n = NN - base; if (n > 256) n = 256;
    if (j < n) sb[j] = batch[base + j];
    __syncthreads();
    float acc = 0.0f;
    int cur = sb[0];
    for (int t = 0; t < n; t++) {
        int g = sb[t];
        if (g != cur) {
            atomicAdd(&gpool[cur * HH + j], acc);
            acc = 0.0f;
            cur = g;
        }
        acc += b2f_lo((uint)h[(size_t)(base + t) * HH + j]);
    }
    atomicAdd(&gpool[cur * HH + j], acc);
}

// ---------------- heads (f32): one block per graph ----------------
__global__ void k_head(const float* __restrict__ gpool, const float* __restrict__ gcnt,
                       const float* __restrict__ Wa1, const float* __restrict__ ba1,
                       const float* __restrict__ Wa2, const float* __restrict__ ba2,
                       const float* __restrict__ Wc1, const float* __restrict__ bc1,
                       const float* __restrict__ Wc2, const float* __restrict__ bc2,
                       float* __restrict__ outp) {
    __shared__ float gv[HH], ha[HH], hc[HH];
    int g = blockIdx.x, j = threadIdx.x;
    float c = gcnt[g];
    c = c > 1.0f ? c : 1.0f;
    gv[j] = gpool[g * HH + j] * __builtin_amdgcn_rcpf(c);
    __syncthreads();
    float a_acc = ba1[j], c_acc = bc1[j];
#pragma unroll 2
    for (int k = 0; k < HH; k += 4) {
        float4 g4 = *reinterpret_cast<const float4*>(&gv[k]);
        const float* WA = Wa1 + k * HH + j;
        const float* WC = Wc1 + k * HH + j;
        a_acc += g4.x * WA[0] + g4.y * WA[HH] + g4.z * WA[2 * HH] + g4.w * WA[3 * HH];
        c_acc += g4.x * WC[0] + g4.y * WC[HH] + g4.z * WC[2 * HH] + g4.w * WC[3 * HH];
    }
    ha[j] = a_acc > 0.0f ? a_acc : 0.0f;
    hc[j] = c_acc > 0.0f ? c_acc : 0.0f;
    __syncthreads();
    if (j < AA) {
        float m = ba2[j];
        for (int k = 0; k < HH; k++) m += ha[k] * Wa2[k * AA + j];
        outp[g * AA + j] = m;
    } else if (j == AA) {
        float v = bc2[0];
        for (int k = 0; k < HH; k++) v += hc[k] * Wc2[k];
        outp[GG * AA + g] = v;
    }
}

extern "C" void kernel_launch(void* const* d_in, const int* in_sizes, int n_in,
                              void* d_out, int out_size, void* d_ws, size_t ws_size,
                              hipStream_t stream) {
    const float* x     = (const float*)d_in[0];
    const int*   ei    = (const int*)d_in[1];
    const int*   batch = (const int*)d_in[2];
    const float* Wl1 = (const float*)d_in[3];
    const float* bl1 = (const float*)d_in[4];
    const float* Wr1 = (const float*)d_in[5];
    const float* Wl2 = (const float*)d_in[6];
    const float* bl2 = (const float*)d_in[7];
    const float* Wr2 = (const float*)d_in[8];
    const float* Wa1 = (const float*)d_in[9];
    const float* ba1 = (const float*)d_in[10];
    const float* Wa2 = (const float*)d_in[11];
    const float* ba2 = (const float*)d_in[12];
    const float* Wc1 = (const float*)d_in[13];
    const float* bc1 = (const float*)d_in[14];
    const float* Wc2 = (const float*)d_in[15];
    const float* bc2 = (const float*)d_in[16];
    float* out = (float*)d_out;

    const int* srcv = ei;
    const int* dstv = ei + NE;

    // workspace layout (bytes, 256-aligned), total ~84.3 MB
    char* ws = (char*)d_ws;
    int*    degi     = (int*)(ws + 0);          // 200192
    int*    offsets  = (int*)(ws + 200192);     // 200448
    int*    cursor   = (int*)(ws + 400640);     // 200192
    int*    blocksum = (int*)(ws + 600832);     // 1024
    int*    blockoff = (int*)(ws + 601856);     // 1024
    float*  gcnt     = (float*)(ws + 602880);   // 256
    float*  gpool    = (float*)(ws + 603136);   // 65536
    int*    csr_src  = (int*)(ws + 668672);     // 6400000
    ushort* xb       = (ushort*)(ws + 7068672); // 12800000  x bf16
    ushort* agg1b    = (ushort*)(ws + 19868672);// 12800000
    ushort* h1b      = (ushort*)(ws + 32668672);// 25600000
    ushort* agg2b    = (ushort*)(ws + 58268672);// 25600000  (h2 in-place)
    ushort* Wt1      = (ushort*)(ws + 83868672);// 131072
    ushort* Wt2      = (ushort*)(ws + 83999744);// 262144 -> end 84261888

    hipMemsetAsync(ws, 0, 200192, stream);            // degi
    hipMemsetAsync(ws + 602880, 0, 65792, stream);    // gcnt + gpool

    k_castx<<<(NN * FIN / 4 + 255) / 256, 256, 0, stream>>>(x, xb);
    k_castw<2 * FIN><<<(HH * 2 * FIN + 255) / 256, 256, 0, stream>>>(Wl1, Wr1, Wt1);
    k_castw<2 * HH> <<<(HH * 2 * HH + 255) / 256, 256, 0, stream>>>(Wl2, Wr2, Wt2);

    k_degi<<<(NE + 255) / 256, 256, 0, stream>>>(dstv, degi);
    k_gdeg<<<(NN + 255) / 256, 256, 0, stream>>>(batch, gcnt);
    k_scan1<<<NB, 256, 0, stream>>>(degi, blocksum);
    k_scan2<<<1, 256, 0, stream>>>(blocksum, blockoff);
    k_scan3<<<NB, 256, 0, stream>>>(degi, blockoff, offsets, cursor);
    k_fill<<<(NE + 255) / 256, 256, 0, stream>>>(srcv, dstv, cursor, csr_src);

    // layer 1
    k_gatherb<FIN><<<(NN + 3) / 4, 256, 0, stream>>>(offsets, csr_src, xb, agg1b);
    k_sage_mfma<2 * FIN><<<(NN + 63) / 64, 256, 0, stream>>>(agg1b, xb, Wt1, bl1, h1b);

    // layer 2 (h2 overwrites agg2b in-place)
    k_gatherb<HH><<<(NN + 3) / 4, 256, 0, stream>>>(offsets, csr_src, h1b, agg2b);
    k_sage_mfma<2 * HH><<<(NN + 63) / 64, 256, 0, stream>>>(agg2b, h1b, Wt2, bl2, agg2b);

    // pool + heads
    k_pool<<<(NN + 255) / 256, 256, 0, stream>>>(agg2b, batch, gpool);
    k_head<<<GG, 256, 0, stream>>>(gpool, gcnt, Wa1, ba1, Wa2, ba2, Wc1, bc1, Wc2, bc2, out);
}